// Round 4
// baseline (869.766 us; speedup 1.0000x reference)
//
#include <hip/hip_runtime.h>
#include <hip/hip_cooperative_groups.h>
#include <math.h>

namespace cg = cooperative_groups;

// EdgeFocusedGraphNetwork — collapsed algebra + bf16-split MFMA.
//
// Validated algebra (rounds 1-2): fe stays rank-structured P[i]+Q[j]+r;
// softmax over i cancels Q, r, b_fe, b_ue, b_attn.  Folds:
//   Wsa  = W_attn @ W_ue                (256x512)
//   Wsab = Wsa[:, :H] @ Wfe1            (256x256)   Wfe1 = W_fe[:, :H]
//   Wueb = W_ue[:, :H] @ Wfe1           (256x256)
// per step (P := i-part of fe):
//   S      = fv@Wsab.T + P@Wsa[:,H:].T
//   P'     = fv@Wueb.T + P@Wue[:,H:].T
//   xhid   = (fv*mask)@W_agg.T + b_agg
//   agg[b] = sigmoid(sum_i softmax_i(S)*xhid)      (j-independent)
//   fv'    = [xhid | agg]@W_uv.T + b_uv
// All GEMMs: f32 = hi+lo bf16 split, 3x mfma_f32_16x16x32_bf16, f32 acc.
// 13 stages, 12 grid syncs. Grid 512 = 2 blocks/CU — guaranteed co-resident
// (launch_bounds caps VGPR; LDS 10KB) so this_grid().sync() cannot deadlock.

typedef float  f32x4  __attribute__((ext_vector_type(4)));
typedef short  bf16x8 __attribute__((ext_vector_type(8)));
typedef short  short4v __attribute__((ext_vector_type(4)));

#define H     256
#define H2    512
#define MROWS 1024
#define NBLK  512
#define NSTAGE 13

__device__ __forceinline__ ushort f2bf(float f) {
    uint u = __float_as_uint(f);
    u += 0x7FFFu + ((u >> 16) & 1u);          // RNE
    return (ushort)(u >> 16);
}
__device__ __forceinline__ float bf2f(ushort h) {
    return __uint_as_float(((uint)h) << 16);
}

struct Args {
    const float *feat, *mask, *b_inp, *b_oup, *b_agg, *b_uv;
    const float *W_fe, *W_inp, *W_oup, *W_ue, *W_agg, *W_uv, *W_attn;
    float *out;
    ushort *featH,*featL, *WinpH,*WinpL, *WueH,*WueL, *WuvH,*WuvL,
           *WoupH,*WoupL, *WattnH,*WattnL, *WaggH,*WaggL, *Wfe1H,*Wfe1L,
           *WsaH,*WsaL, *WsabH,*WsabL, *WuebH,*WuebL,
           *fvH,*fvL, *fvmH,*fvmL, *ca0H,*ca0L, *ca1H,*ca1L, *xcH,*xcL;
    float *S;
};

struct GSeg { const ushort *xh,*xl,*wh,*wl; int ldx, ldw, nks, wtrans; };

__device__ __forceinline__ void issue_loads(const GSeg& s, int bm, int bn,
                                            int ks, int lr, int lc, short4v r[4])
{
    int xo = (bm + lr) * s.ldx + ks * 32 + lc;
    r[0] = *(const short4v*)(s.xh + xo);
    r[1] = *(const short4v*)(s.xl + xo);
    int wo;
    if (s.wtrans) wo = (ks * 32 + lr) * s.ldw + bn + lc;   // src [k][n]
    else          wo = (bn + lr) * s.ldw + ks * 32 + lc;   // src [n][k]
    r[2] = *(const short4v*)(s.wh + wo);
    r[3] = *(const short4v*)(s.wl + wo);
}

__device__ __forceinline__ void store_stage(ushort* lds, int wtrans,
                                            int lr, int lc, const short4v r[4])
{
    *(short4v*)(lds +    0 + lr * 40 + lc) = r[0];
    *(short4v*)(lds + 1280 + lr * 40 + lc) = r[1];
    if (!wtrans) {
        *(short4v*)(lds + 2560 + lr * 40 + lc) = r[2];
        *(short4v*)(lds + 3840 + lr * 40 + lc) = r[3];
    } else {
        #pragma unroll
        for (int i = 0; i < 4; ++i) {
            lds[2560 + (lc + i) * 40 + lr] = (ushort)r[2][i];
            lds[3840 + (lc + i) * 40 + lr] = (ushort)r[3][i];
        }
    }
}

// mode: 0 = f32 out, 1 = split-pair out, 2 = split-pair + masked split-pair
__device__ void run_gemm(const GSeg segs[2], int nseg, int mode,
                         float* yf, int ldy,
                         ushort* yh, ushort* yl, int ldn,
                         ushort* y2h, ushort* y2l,
                         const float* bias, const float* mask,
                         int bm, int bn, int tid, ushort* lds)
{
    const int lr = tid >> 3, lc = (tid & 7) << 2;
    const int l  = tid & 63, w = tid >> 6;
    const int qm = (w >> 1) << 4, qn = (w & 1) << 4;
    const int rl = l & 15, kg = l >> 4;

    const int n0 = segs[0].nks;
    const int total = n0 + (nseg > 1 ? segs[1].nks : 0);

    short4v regs[4];
    issue_loads(segs[0], bm, bn, 0, lr, lc, regs);

    f32x4 acc = {0.f, 0.f, 0.f, 0.f};
    const ushort* pax = lds +        (qm + rl) * 40 + kg * 8;
    const ushort* pbx = lds + 2560 + (qn + rl) * 40 + kg * 8;

    for (int g = 0; g < total; ++g) {
        const int sc = (g < n0) ? 0 : 1;
        __syncthreads();
        store_stage(lds, segs[sc].wtrans, lr, lc, regs);
        if (g + 1 < total) {
            const int sn = (g + 1 < n0) ? 0 : 1;
            issue_loads(segs[sn], bm, bn, (sn == 0) ? g + 1 : g + 1 - n0,
                        lr, lc, regs);
        }
        __syncthreads();
        bf16x8 ah = *(const bf16x8*)(pax);
        bf16x8 al = *(const bf16x8*)(pax + 1280);
        bf16x8 bh = *(const bf16x8*)(pbx);
        bf16x8 bl = *(const bf16x8*)(pbx + 1280);
        acc = __builtin_amdgcn_mfma_f32_16x16x32_bf16(ah, bh, acc, 0, 0, 0);
        acc = __builtin_amdgcn_mfma_f32_16x16x32_bf16(ah, bl, acc, 0, 0, 0);
        acc = __builtin_amdgcn_mfma_f32_16x16x32_bf16(al, bh, acc, 0, 0, 0);
    }

    // epilogue: C/D map: col = lane&15, row = (lane>>4)*4 + reg
    const int col = bn + qn + rl;
    const float bv = bias ? bias[col] : 0.f;
    #pragma unroll
    for (int i = 0; i < 4; ++i) {
        const int row = bm + qm + kg * 4 + i;
        const float v = acc[i] + bv;
        if (mode == 0) {
            yf[row * ldy + col] = v;
        } else {
            ushort hh = f2bf(v);
            yh[row * ldn + col] = hh;
            yl[row * ldn + col] = f2bf(v - bf2f(hh));
            if (mode == 2) {
                const float vm = v * mask[row];
                ushort mh = f2bf(vm);
                y2h[row * ldn + col] = mh;
                y2l[row * ldn + col] = f2bf(vm - bf2f(mh));
            }
        }
    }
}

// per (b, 32-h group): softmax over i=0..127 of S, weighted by xhid,
// sigmoid, broadcast split-pair agg into xc[:, H+h].
__device__ void run_sm(const Args& a, int u, int tid, ushort* lds)
{
    const int b = u >> 3, hg = u & 7;
    const int th = tid & 31, ti = tid >> 5;      // 32 h x 8 i-groups(16)
    const int row0 = b * 128;
    const int col = hg * 32 + th;

    float v[16];
    float m = -3.402823466e38f;
    #pragma unroll
    for (int ii = 0; ii < 16; ++ii) {
        v[ii] = a.S[(row0 + ti * 16 + ii) * H + col];
        m = fmaxf(m, v[ii]);
    }
    float* redm = (float*)lds;            // 256
    float* reds = redm + 256;             // 256
    float* reda = reds + 256;             // 256  (3KB < 10KB)
    redm[ti * 32 + th] = m;
    __syncthreads();
    float M = -3.402823466e38f;
    #pragma unroll
    for (int g = 0; g < 8; ++g) M = fmaxf(M, redm[g * 32 + th]);

    float s = 0.f, acc = 0.f;
    #pragma unroll
    for (int ii = 0; ii < 16; ++ii) {
        const int r = row0 + ti * 16 + ii;
        const float xh = bf2f(a.xcH[r * H2 + col]) + bf2f(a.xcL[r * H2 + col]);
        const float e = __expf(v[ii] - M);
        s += e;
        acc = fmaf(e, xh, acc);
    }
    reds[ti * 32 + th] = s;
    reda[ti * 32 + th] = acc;
    __syncthreads();
    float S8 = 0.f, A8 = 0.f;
    #pragma unroll
    for (int g = 0; g < 8; ++g) { S8 += reds[g * 32 + th]; A8 += reda[g * 32 + th]; }
    const float gv = 1.f / (1.f + __expf(-(A8 / S8)));
    const ushort gh = f2bf(gv);
    const ushort gl = f2bf(gv - bf2f(gh));
    #pragma unroll
    for (int ii = 0; ii < 16; ++ii) {
        const int r = row0 + ti * 16 + ii;
        a.xcH[r * H2 + H + col] = gh;
        a.xcL[r * H2 + H + col] = gl;
    }
}

__device__ void run_prep(const Args& a, int bid, int tid)
{
    const float* src[8] = {a.feat, a.W_inp, a.W_ue, a.W_uv,
                           a.W_oup, a.W_attn, a.W_agg, a.W_fe};
    ushort* dh[8] = {a.featH, a.WinpH, a.WueH, a.WuvH,
                     a.WoupH, a.WattnH, a.WaggH, a.Wfe1H};
    ushort* dl[8] = {a.featL, a.WinpL, a.WueL, a.WuvL,
                     a.WoupL, a.WattnL, a.WaggL, a.Wfe1L};
    const int n[8]  = {524288, 131072, 131072, 131072, 131072, 65536, 65536, 65536};
    const int strided[8] = {0,0,0,0,0,0,0,1};   // W_fe: cols 0..255 of 512
    for (int e = 0; e < 8; ++e) {
        const float* sp = src[e];
        ushort *hp = dh[e], *lp = dl[e];
        for (int i = bid * 256 + tid; i < n[e]; i += NBLK * 256) {
            int off = strided[e] ? ((i >> 8) * 512 + (i & 255)) : i;
            float vv = sp[off];
            ushort hh = f2bf(vv);
            hp[i] = hh;
            lp[i] = f2bf(vv - bf2f(hh));
        }
    }
}

__device__ void run_stage(const Args& a, int st, int bid, int tid, ushort* lds)
{
    GSeg sg[2];
    if (st == 0) { run_prep(a, bid, tid); return; }

    if (st == 1) {            // fv0 (256 units) || Wsa (128 units)
        for (int u = bid; u < 384; u += NBLK) {
            if (u < 256) {
                int bm = (u >> 3) << 5, bn = (u & 7) << 5;
                sg[0] = {a.featH, a.featL, a.WinpH, a.WinpL, H2, H2, 16, 0};
                run_gemm(sg, 1, 2, nullptr, 0, a.fvH, a.fvL, H, a.fvmH, a.fvmL,
                         a.b_inp, a.mask, bm, bn, tid, lds);
            } else {
                int v = u - 256;                     // 256x512: 8m x 16n
                int bm = (v >> 4) << 5, bn = (v & 15) << 5;
                sg[0] = {a.WattnH, a.WattnL, a.WueH, a.WueL, H, H2, 8, 1};
                run_gemm(sg, 1, 1, nullptr, 0, a.WsaH, a.WsaL, H2, nullptr, nullptr,
                         nullptr, nullptr, bm, bn, tid, lds);
            }
        }
        return;
    }
    if (st == 2) {            // Wsab(64) | Wueb(64) | P0(256) | xhid0(256)
        for (int u = bid; u < 640; u += NBLK) {
            if (u < 64) {
                int bm = (u >> 3) << 5, bn = (u & 7) << 5;
                sg[0] = {a.WsaH, a.WsaL, a.Wfe1H, a.Wfe1L, H2, H, 8, 1};
                run_gemm(sg, 1, 1, nullptr, 0, a.WsabH, a.WsabL, H, nullptr, nullptr,
                         nullptr, nullptr, bm, bn, tid, lds);
            } else if (u < 128) {
                int v = u - 64;
                int bm = (v >> 3) << 5, bn = (v & 7) << 5;
                sg[0] = {a.WueH, a.WueL, a.Wfe1H, a.Wfe1L, H2, H, 8, 1};
                run_gemm(sg, 1, 1, nullptr, 0, a.WuebH, a.WuebL, H, nullptr, nullptr,
                         nullptr, nullptr, bm, bn, tid, lds);
            } else if (u < 384) {
                int v = u - 128;
                int bm = (v >> 3) << 5, bn = (v & 7) << 5;
                sg[0] = {a.fvH, a.fvL, a.Wfe1H, a.Wfe1L, H, H, 8, 0};
                run_gemm(sg, 1, 1, nullptr, 0, a.ca0H, a.ca0L, H, nullptr, nullptr,
                         nullptr, nullptr, bm, bn, tid, lds);
            } else {
                int v = u - 384;
                int bm = (v >> 3) << 5, bn = (v & 7) << 5;
                sg[0] = {a.fvmH, a.fvmL, a.WaggH, a.WaggL, H, H, 8, 0};
                run_gemm(sg, 1, 1, nullptr, 0, a.xcH, a.xcL, H2, nullptr, nullptr,
                         a.b_agg, nullptr, bm, bn, tid, lds);
            }
        }
        return;
    }

    if (st == 3 || st == 6 || st == 9) {       // ph0(t): S || P' || xhid_t
        const int t = (st - 3) / 3;
        ushort* curH = (t & 1) ? a.ca1H : a.ca0H;
        ushort* curL = (t & 1) ? a.ca1L : a.ca0L;
        ushort* nxtH = (t & 1) ? a.ca0H : a.ca1H;
        ushort* nxtL = (t & 1) ? a.ca0L : a.ca1L;
        const int xbase = (t < 2) ? 512 : 256;             // xhid unit base
        const int nunits = (t == 1) ? 768 : 512;           // t=0: S+P'; t=2: S+xhid
        for (int u = bid; u < nunits; u += NBLK) {
            if (u < 256) {                     // S
                int bm = (u >> 3) << 5, bn = (u & 7) << 5;
                sg[0] = {a.fvH, a.fvL, a.WsabH, a.WsabL, H, H, 8, 0};
                sg[1] = {curH, curL, a.WsaH + 256, a.WsaL + 256, H, H2, 8, 0};
                run_gemm(sg, 2, 0, a.S, H, nullptr, nullptr, 0, nullptr, nullptr,
                         nullptr, nullptr, bm, bn, tid, lds);
            } else if (t < 2 && u < 512) {     // P'
                int v = u - 256;
                int bm = (v >> 3) << 5, bn = (v & 7) << 5;
                sg[0] = {a.fvH, a.fvL, a.WuebH, a.WuebL, H, H, 8, 0};
                sg[1] = {curH, curL, a.WueH + 256, a.WueL + 256, H, H2, 8, 0};
                run_gemm(sg, 2, 1, nullptr, 0, nxtH, nxtL, H, nullptr, nullptr,
                         nullptr, nullptr, bm, bn, tid, lds);
            } else if (t >= 1) {               // xhid_t (t=0 done in st2)
                int v = u - xbase;
                if (v >= 0 && v < 256) {
                    int bm = (v >> 3) << 5, bn = (v & 7) << 5;
                    sg[0] = {a.fvmH, a.fvmL, a.WaggH, a.WaggL, H, H, 8, 0};
                    run_gemm(sg, 1, 1, nullptr, 0, a.xcH, a.xcL, H2, nullptr, nullptr,
                             a.b_agg, nullptr, bm, bn, tid, lds);
                }
            }
        }
        return;
    }
    if (st == 4 || st == 7 || st == 10) {      // sm(t): 64 units
        for (int u = bid; u < 64; u += NBLK) run_sm(a, u, tid, lds);
        return;
    }
    if (st == 5 || st == 8 || st == 11) {      // ph1(t): fv' (256 units)
        for (int u = bid; u < 256; u += NBLK) {
            int bm = (u >> 3) << 5, bn = (u & 7) << 5;
            sg[0] = {a.xcH, a.xcL, a.WuvH, a.WuvL, H2, H2, 16, 0};
            run_gemm(sg, 1, 2, nullptr, 0, a.fvH, a.fvL, H, a.fvmH, a.fvmL,
                     a.b_uv, a.mask, bm, bn, tid, lds);
        }
        return;
    }
    // st == 12: out = fv3 @ W_oup.T + b_oup   (1024x512, 32m x 16n = 512 units)
    for (int u = bid; u < 512; u += NBLK) {
        int bm = (u >> 4) << 5, bn = (u & 15) << 5;
        sg[0] = {a.fvH, a.fvL, a.WoupH, a.WoupL, H, H, 8, 0};
        run_gemm(sg, 1, 0, a.out, H2, nullptr, nullptr, 0, nullptr, nullptr,
                 a.b_oup, nullptr, bm, bn, tid, lds);
    }
}

__global__ __launch_bounds__(256, 2) void efgn(Args a, int s0, int s1)
{
    __shared__ ushort lds[5120];   // 10240 B
    const int bid = blockIdx.x, tid = threadIdx.x;
    for (int s = s0; s < s1; ++s) {
        run_stage(a, s, bid, tid, lds);
        if (s + 1 < s1) cg::this_grid().sync();
    }
}

extern "C" void kernel_launch(void* const* d_in, const int* in_sizes, int n_in,
                              void* d_out, int out_size, void* d_ws, size_t ws_size,
                              hipStream_t stream)
{
    Args a;
    a.feat   = (const float*)d_in[0];
    a.mask   = (const float*)d_in[1];
    a.W_inp  = (const float*)d_in[2];
    a.b_inp  = (const float*)d_in[3];
    a.W_oup  = (const float*)d_in[4];
    a.b_oup  = (const float*)d_in[5];
    a.W_fe   = (const float*)d_in[6];   // [7] b_fe cancels
    a.W_ue   = (const float*)d_in[8];   // [9] b_ue cancels
    a.W_agg  = (const float*)d_in[10];
    a.b_agg  = (const float*)d_in[11];
    a.W_uv   = (const float*)d_in[12];
    a.b_uv   = (const float*)d_in[13];
    a.W_attn = (const float*)d_in[14];  // [15] b_attn cancels
    a.out    = (float*)d_out;

    float* fp = (float*)d_ws;
    a.S = fp; fp += MROWS * H;
    ushort* up = (ushort*)fp;
    auto take = [&](int n) { ushort* p = up; up += n; return p; };
    a.featH = take(524288); a.featL = take(524288);
    a.WinpH = take(131072); a.WinpL = take(131072);
    a.WueH  = take(131072); a.WueL  = take(131072);
    a.WuvH  = take(131072); a.WuvL  = take(131072);
    a.WoupH = take(131072); a.WoupL = take(131072);
    a.WattnH= take(65536);  a.WattnL= take(65536);
    a.WaggH = take(65536);  a.WaggL = take(65536);
    a.Wfe1H = take(65536);  a.Wfe1L = take(65536);
    a.WsaH  = take(131072); a.WsaL  = take(131072);
    a.WsabH = take(65536);  a.WsabL = take(65536);
    a.WuebH = take(65536);  a.WuebL = take(65536);
    a.fvH   = take(262144); a.fvL   = take(262144);
    a.fvmH  = take(262144); a.fvmL  = take(262144);
    a.ca0H  = take(262144); a.ca0L  = take(262144);
    a.ca1H  = take(262144); a.ca1L  = take(262144);
    a.xcH   = take(524288); a.xcL   = take(524288);

    int s0 = 0, s1 = NSTAGE;
    void* params[] = { (void*)&a, (void*)&s0, (void*)&s1 };
    hipError_t e = hipLaunchCooperativeKernel((const void*)efgn,
                                              dim3(NBLK), dim3(256),
                                              params, 0, stream);
    if (e != hipSuccess) {
        (void)hipGetLastError();  // clear sticky error, fall back
        for (int s = 0; s < NSTAGE; ++s)
            efgn<<<dim3(NBLK), dim3(256), 0, stream>>>(a, s, s + 1);
    }
}

// Round 7
// 276.485 us; speedup vs baseline: 3.1458x; 3.1458x over previous
//
#include <hip/hip_runtime.h>
#include <math.h>

// EdgeFocusedGraphNetwork — collapsed algebra, 14 plain launches, no sync.
//
// Algebra (HW-validated r1/r4): fe stays rank-structured P[i]+Q[j]+r; softmax
// over i cancels Q, r, b_fe, b_ue, b_attn. Folds:
//   Wsa = W_attn@W_ue ; Wsab = Wsa[:,:H]@Wfe1 ; Wueb = W_ue[:,:H]@Wfe1.
// Per step: S = fv@Wsab.T + P@Wsa[:,H:].T ; P' = fv@Wueb.T + P@W_ue[:,H:].T ;
//   xhid = (fv*mask)@W_agg.T + b_agg ; agg[b,h] = sigmoid(sm-weighted sum) ;
//   fv' = xhid@W_uv[:,:H].T + (c_b + b_uv),  c_b[n] = sum_h agg[b,h]*W_uv[n,H+h].
//
// r2/r4 lesson: grid-wide sync ~60us each (cross-XCD L2 coherence) — banned.
// r5 audit: 8-block persistent main = 8 CUs = 130us MFMA floor — banned.
// This round: each dependency stage is its own small launch on a WIDE grid;
// one-wave blocks compute 32x32 tiles directly from L2 (no LDS staging, no
// barriers -> compiler pipelines k-loop). f32 = hi+lo bf16 split, 3 MFMA per
// k-step (error ~1.5e-5 rel, passed r4 at absmax 2e-3).

typedef float f32x4  __attribute__((ext_vector_type(4)));
typedef short bf16x8 __attribute__((ext_vector_type(8)));

#define H  256
#define H2 512

__device__ __forceinline__ ushort f2bf(float f) {
    uint u = __float_as_uint(f);
    u += 0x7FFFu + ((u >> 16) & 1u);          // RNE
    return (ushort)(u >> 16);
}
__device__ __forceinline__ float bf2f(ushort h) {
    return __uint_as_float(((uint)h) << 16);
}

struct Args {
    const float *feat, *mask, *b_inp, *b_oup, *b_agg, *b_uv;
    const float *W_fe, *W_inp, *W_oup, *W_ue, *W_agg, *W_uv, *W_attn;
    float *out;
    float *Wsa, *S, *Cb;
    ushort *featH,*featL, *WfeH,*WfeL, *WinpH,*WinpL, *WueH,*WueL,
           *WuvH,*WuvL, *WoupH,*WoupL, *WaggH,*WaggL,
           *WsaH,*WsaL, *WsabH,*WsabL, *WuebH,*WuebL,
           *fvH,*fvL, *fvmH,*fvmL, *xhH,*xhL, *p0H,*p0L, *p1H,*p1L;
};

struct Seg { const ushort *ah,*al,*bh,*bl; int lda, ldb, nk32; };

// One-wave 32x32-tile GEMM, operands direct from global (L2-hot).
// Frags (HW-verified r4): A row = lane&15 (+16*mi), k = ks*32+(lane>>4)*8,
// 8 contiguous bf16 = one dwordx4. Per K=32 step: 8 loads + 12 MFMA.
// C/D map: col = lane&15, row = (lane>>4)*4 + reg.
// MODE 0: f32 out. MODE 1: hi/lo planes (ld H). MODE 2: planes + masked planes.
template<int MODE>
__device__ void wave_gemm32(const Seg* segs, int nseg,
                            float* yf, int ldy,
                            ushort* yh, ushort* yl, ushort* ymh, ushort* yml,
                            const float* bias, const float* cvec,
                            const float* mask, int bm, int bn, int lane)
{
    const int rl = lane & 15, kq = lane >> 4;
    f32x4 acc[2][2] = {};

    for (int s = 0; s < nseg; ++s) {
        const Seg sg = segs[s];
        for (int ks = 0; ks < sg.nk32; ++ks) {
            const int kb = ks * 32 + kq * 8;
            bf16x8 ah[2], al[2], bh[2], bl[2];
            #pragma unroll
            for (int mi = 0; mi < 2; ++mi) {
                const size_t ro = (size_t)(bm + mi * 16 + rl) * sg.lda + kb;
                ah[mi] = *(const bf16x8*)(sg.ah + ro);
                al[mi] = *(const bf16x8*)(sg.al + ro);
            }
            #pragma unroll
            for (int ni = 0; ni < 2; ++ni) {
                const size_t co = (size_t)(bn + ni * 16 + rl) * sg.ldb + kb;
                bh[ni] = *(const bf16x8*)(sg.bh + co);
                bl[ni] = *(const bf16x8*)(sg.bl + co);
            }
            #pragma unroll
            for (int mi = 0; mi < 2; ++mi)
                #pragma unroll
                for (int ni = 0; ni < 2; ++ni) {
                    acc[mi][ni] = __builtin_amdgcn_mfma_f32_16x16x32_bf16(
                        ah[mi], bh[ni], acc[mi][ni], 0, 0, 0);
                    acc[mi][ni] = __builtin_amdgcn_mfma_f32_16x16x32_bf16(
                        ah[mi], bl[ni], acc[mi][ni], 0, 0, 0);
                    acc[mi][ni] = __builtin_amdgcn_mfma_f32_16x16x32_bf16(
                        al[mi], bh[ni], acc[mi][ni], 0, 0, 0);
                }
        }
    }
    #pragma unroll
    for (int mi = 0; mi < 2; ++mi)
        #pragma unroll
        for (int ni = 0; ni < 2; ++ni) {
            const int col = bn + ni * 16 + rl;
            float bv = bias ? bias[col] : 0.f;
            if (MODE == 2 && cvec) bv += cvec[col];
            #pragma unroll
            for (int j = 0; j < 4; ++j) {
                const int row = bm + mi * 16 + kq * 4 + j;
                const float v = acc[mi][ni][j] + bv;
                if (MODE == 0) {
                    yf[(size_t)row * ldy + col] = v;
                } else {
                    const ushort hh = f2bf(v);
                    yh[(size_t)row * H + col] = hh;
                    yl[(size_t)row * H + col] = f2bf(v - bf2f(hh));
                    if (MODE == 2) {
                        const float mv = v * mask[row];
                        const ushort mh = f2bf(mv);
                        ymh[(size_t)row * H + col] = mh;
                        yml[(size_t)row * H + col] = f2bf(mv - bf2f(mh));
                    }
                }
            }
        }
}

// ---- L0: hi/lo splits (1024 blocks)  ||  Wsa = W_attn@W_ue f32 (512) ------
__global__ __launch_bounds__(256) void k_prep(Args a)
{
    const int bid = blockIdx.x, tid = threadIdx.x;
    if (bid < 1024) {
        const float* src[7] = {a.feat, a.W_fe, a.W_inp, a.W_ue, a.W_uv,
                               a.W_oup, a.W_agg};
        ushort* dh[7] = {a.featH, a.WfeH, a.WinpH, a.WueH, a.WuvH,
                         a.WoupH, a.WaggH};
        ushort* dl[7] = {a.featL, a.WfeL, a.WinpL, a.WueL, a.WuvL,
                         a.WoupL, a.WaggL};
        const int n[7] = {524288, 131072, 131072, 131072, 131072, 131072, 65536};
        for (int e = 0; e < 7; ++e) {
            const float* sp = src[e];
            ushort *hp = dh[e], *lp = dl[e];
            for (int i = bid * 256 + tid; i < n[e]; i += 1024 * 256) {
                const float v = sp[i];
                const ushort hh = f2bf(v);
                hp[i] = hh;
                lp[i] = f2bf(v - bf2f(hh));
            }
        }
    } else {
        const int idx = (bid - 1024) * 256 + tid;       // 131072 = 256x512
        const int i = idx >> 9, j = idx & 511;
        float acc = 0.f;
        const float* wa = a.W_attn + i * 256;
        const float* wu = a.W_ue + j;
        #pragma unroll 4
        for (int k = 0; k < 256; ++k)
            acc = fmaf(wa[k], wu[(size_t)k * 512], acc);
        a.Wsa[idx] = acc;
        const ushort hh = f2bf(acc);
        a.WsaH[idx] = hh;
        a.WsaL[idx] = f2bf(acc - bf2f(hh));
    }
}

// ---- L1: Wsab = Wsa[:,:H]@Wfe1 ; Wueb = W_ue[:,:H]@Wfe1 (f32 dot) ---------
__global__ __launch_bounds__(256) void k_folds(Args a)
{
    const int idx = blockIdx.x * 256 + threadIdx.x;     // 131072
    const int which = idx >> 16;
    const int o = idx & 65535, i = o >> 8, j = o & 255;
    const float* xrow = (which == 0) ? (a.Wsa + i * 512) : (a.W_ue + i * 512);
    const float* wcol = a.W_fe + j;
    float acc = 0.f;
    #pragma unroll 4
    for (int k = 0; k < 256; ++k)
        acc = fmaf(xrow[k], wcol[(size_t)k * 512], acc);
    ushort* hp = (which == 0) ? a.WsabH : a.WuebH;
    ushort* lp = (which == 0) ? a.WsabL : a.WuebL;
    const ushort hh = f2bf(acc);
    hp[o] = hh;
    lp[o] = f2bf(acc - bf2f(hh));
}

// ---- L2: fv0 = feat@Winp.T + b_inp (K=512) -> fv + fvm planes (256 blocks)
__global__ __launch_bounds__(64) void k_fv0(Args a)
{
    const int bid = blockIdx.x;
    const int bm = (bid >> 3) << 5, bn = (bid & 7) << 5;
    Seg sg[1] = {{a.featH, a.featL, a.WinpH, a.WinpL, H2, H2, 16}};
    wave_gemm32<2>(sg, 1, nullptr, 0, a.fvH, a.fvL, a.fvmH, a.fvmL,
                   a.b_inp, nullptr, a.mask, bm, bn, threadIdx.x);
}

// ---- L3: P0 = fv0@Wfe1.T (256) || xhid0 = fvm@Wagg.T + b_agg (256) --------
__global__ __launch_bounds__(64) void k_p0xh0(Args a)
{
    const int u = blockIdx.x, v = u & 255;
    const int bm = (v >> 3) << 5, bn = (v & 7) << 5;
    if (u < 256) {
        Seg sg[1] = {{a.fvH, a.fvL, a.WfeH, a.WfeL, H, H2, 8}};
        wave_gemm32<1>(sg, 1, nullptr, 0, a.p0H, a.p0L, nullptr, nullptr,
                       nullptr, nullptr, nullptr, bm, bn, threadIdx.x);
    } else {
        Seg sg[1] = {{a.fvmH, a.fvmL, a.WaggH, a.WaggL, H, H, 8}};
        wave_gemm32<1>(sg, 1, nullptr, 0, a.xhH, a.xhL, nullptr, nullptr,
                       a.b_agg, nullptr, nullptr, bm, bn, threadIdx.x);
    }
}

// ---- L4+3t: S (256) || P' (256, t<2) || xhid_t (256, t>=1) ----------------
__global__ __launch_bounds__(64) void k_sph(Args a, int t)
{
    const int u = blockIdx.x, v = u & 255;
    const int bm = (v >> 3) << 5, bn = (v & 7) << 5;
    const ushort* pch = (t & 1) ? a.p1H : a.p0H;
    const ushort* pcl = (t & 1) ? a.p1L : a.p0L;
    ushort* pnh = (t & 1) ? a.p0H : a.p1H;
    ushort* pnl = (t & 1) ? a.p0L : a.p1L;
    const int which = (u < 256) ? 0 : (u < 512 ? (t < 2 ? 1 : 2) : 2);
    if (which == 0) {          // S = fv@Wsab.T + P@Wsa[:,H:].T  (f32)
        Seg sg[2] = {{a.fvH, a.fvL, a.WsabH, a.WsabL, H, H, 8},
                     {pch, pcl, a.WsaH + H, a.WsaL + H, H, H2, 8}};
        wave_gemm32<0>(sg, 2, a.S, H, nullptr, nullptr, nullptr, nullptr,
                       nullptr, nullptr, nullptr, bm, bn, threadIdx.x);
    } else if (which == 1) {   // P' = fv@Wueb.T + P@W_ue[:,H:].T
        Seg sg[2] = {{a.fvH, a.fvL, a.WuebH, a.WuebL, H, H, 8},
                     {pch, pcl, a.WueH + H, a.WueL + H, H, H2, 8}};
        wave_gemm32<1>(sg, 2, nullptr, 0, pnh, pnl, nullptr, nullptr,
                       nullptr, nullptr, nullptr, bm, bn, threadIdx.x);
    } else {                   // xhid = fvm@Wagg.T + b_agg
        Seg sg[1] = {{a.fvmH, a.fvmL, a.WaggH, a.WaggL, H, H, 8}};
        wave_gemm32<1>(sg, 1, nullptr, 0, a.xhH, a.xhL, nullptr, nullptr,
                       a.b_agg, nullptr, nullptr, bm, bn, threadIdx.x);
    }
}

// ---- L5+3t: per-batch softmax over i + agg + rank-1 fold c_b (8 blocks) ---
__global__ __launch_bounds__(512) void k_sm(Args a)
{
    __shared__ float smem[2304];
    float* redm = smem;            // 512
    float* reds = smem + 512;      // 512
    float* reda = smem + 1024;     // 512
    float* aggv = smem + 1536;     // 256
    float* cpart = smem + 1792;    // 512
    const int b = blockIdx.x, tid = threadIdx.x;
    const int h = tid & 255, ig = tid >> 8;          // 2 groups x 64 rows
    const int row0 = b * 128 + ig * 64;
    const float*  Sp = a.S + (size_t)row0 * H + h;
    const ushort* xh = a.xhH + (size_t)row0 * H + h;
    const ushort* xl = a.xhL + (size_t)row0 * H + h;

    float m = -3.402823466e38f, s = 0.f, acc = 0.f;
    for (int ii = 0; ii < 64; ++ii) {
        const float v = Sp[(size_t)ii * H];
        const float x = bf2f(xh[(size_t)ii * H]) + bf2f(xl[(size_t)ii * H]);
        const float nm = fmaxf(m, v);
        const float sc = __expf(m - nm);
        const float e  = __expf(v - nm);
        s = s * sc + e;
        acc = acc * sc + e * x;
        m = nm;
    }
    redm[ig * 256 + h] = m; reds[ig * 256 + h] = s; reda[ig * 256 + h] = acc;
    __syncthreads();
    {
        const float m0 = redm[h], m1 = redm[256 + h];
        const float M = fmaxf(m0, m1);
        const float S2 = reds[h] * __expf(m0 - M) + reds[256 + h] * __expf(m1 - M);
        const float A2 = reda[h] * __expf(m0 - M) + reda[256 + h] * __expf(m1 - M);
        const float g = 1.f / (1.f + __expf(-(A2 / S2)));
        if (ig == 0) aggv[h] = g;
    }
    __syncthreads();
    {   // c_b[n] = sum_h aggv[h] * W_uv[n, H+h]   (hi+lo planes)
        const int n = tid >> 1, half = tid & 1;
        const ushort* wh = a.WuvH + (size_t)n * H2 + H + half * 128;
        const ushort* wl = a.WuvL + (size_t)n * H2 + H + half * 128;
        const float* av = aggv + half * 128;
        float c = 0.f;
        for (int q = 0; q < 16; ++q) {
            bf16x8 vh = *(const bf16x8*)(wh + q * 8);
            bf16x8 vl = *(const bf16x8*)(wl + q * 8);
            #pragma unroll
            for (int j = 0; j < 8; ++j)
                c += av[q * 8 + j] * (bf2f((ushort)vh[j]) + bf2f((ushort)vl[j]));
        }
        cpart[tid] = c;
    }
    __syncthreads();
    if (tid < 256) a.Cb[b * H + tid] = cpart[2 * tid] + cpart[2 * tid + 1];
}

// ---- L6+3t: fv' = xhid@W_uv[:,:H].T + (c_b + b_uv) -> fv + fvm (256) ------
__global__ __launch_bounds__(64) void k_fv(Args a)
{
    const int bid = blockIdx.x;
    const int bm = (bid >> 3) << 5, bn = (bid & 7) << 5;
    Seg sg[1] = {{a.xhH, a.xhL, a.WuvH, a.WuvL, H, H2, 8}};
    wave_gemm32<2>(sg, 1, nullptr, 0, a.fvH, a.fvL, a.fvmH, a.fvmL,
                   a.b_uv, a.Cb + (bm >> 7) * H, a.mask, bm, bn, threadIdx.x);
}

// ---- L13: out = fv3@Woup.T + b_oup  (1024x512, 512 blocks) ----------------
__global__ __launch_bounds__(64) void k_out(Args a)
{
    const int bid = blockIdx.x;
    const int bm = (bid >> 4) << 5, bn = (bid & 15) << 5;
    Seg sg[1] = {{a.fvH, a.fvL, a.WoupH, a.WoupL, H, H, 8}};
    wave_gemm32<0>(sg, 1, a.out, H2, nullptr, nullptr, nullptr, nullptr,
                   a.b_oup, nullptr, nullptr, bm, bn, threadIdx.x);
}

extern "C" void kernel_launch(void* const* d_in, const int* in_sizes, int n_in,
                              void* d_out, int out_size, void* d_ws, size_t ws_size,
                              hipStream_t stream)
{
    Args a;
    a.feat   = (const float*)d_in[0];
    a.mask   = (const float*)d_in[1];
    a.W_inp  = (const float*)d_in[2];
    a.b_inp  = (const float*)d_in[3];
    a.W_oup  = (const float*)d_in[4];
    a.b_oup  = (const float*)d_in[5];
    a.W_fe   = (const float*)d_in[6];   // [7] b_fe cancels
    a.W_ue   = (const float*)d_in[8];   // [9] b_ue cancels
    a.W_agg  = (const float*)d_in[10];
    a.b_agg  = (const float*)d_in[11];
    a.W_uv   = (const float*)d_in[12];
    a.b_uv   = (const float*)d_in[13];
    a.W_attn = (const float*)d_in[14];  // [15] b_attn cancels
    a.out    = (float*)d_out;

    float* fp = (float*)d_ws;
    a.Wsa = fp; fp += 131072;
    a.S   = fp; fp += 262144;
    a.Cb  = fp; fp += 2048;
    ushort* up = (ushort*)fp;
    auto take = [&](int n) { ushort* p = up; up += n; return p; };
    a.featH = take(524288); a.featL = take(524288);
    a.WfeH  = take(131072); a.WfeL  = take(131072);
    a.WinpH = take(131072); a.WinpL = take(131072);
    a.WueH  = take(131072); a.WueL  = take(131072);
    a.WuvH  = take(131072); a.WuvL  = take(131072);
    a.WoupH = take(131072); a.WoupL = take(131072);
    a.WaggH = take(65536);  a.WaggL = take(65536);
    a.WsaH  = take(131072); a.WsaL  = take(131072);
    a.WsabH = take(65536);  a.WsabL = take(65536);
    a.WuebH = take(65536);  a.WuebL = take(65536);
    a.fvH   = take(262144); a.fvL   = take(262144);
    a.fvmH  = take(262144); a.fvmL  = take(262144);
    a.xhH   = take(262144); a.xhL   = take(262144);
    a.p0H   = take(262144); a.p0L   = take(262144);
    a.p1H   = take(262144); a.p1L   = take(262144);

    k_prep <<<dim3(1536), dim3(256), 0, stream>>>(a);
    k_folds<<<dim3(512),  dim3(256), 0, stream>>>(a);
    k_fv0  <<<dim3(256),  dim3(64),  0, stream>>>(a);
    k_p0xh0<<<dim3(512),  dim3(64),  0, stream>>>(a);
    for (int t = 0; t < 3; ++t) {
        const int nblk = (t == 1) ? 768 : 512;   // t=0: S+P'; t=1: +xh; t=2: S+xh
        k_sph<<<dim3(nblk), dim3(64),  0, stream>>>(a, t);
        k_sm <<<dim3(8),    dim3(512), 0, stream>>>(a);
        k_fv <<<dim3(256),  dim3(64),  0, stream>>>(a);
    }
    k_out  <<<dim3(512),  dim3(64),  0, stream>>>(a);
}